// Round 2
// baseline (435.073 us; speedup 1.0000x reference)
//
#include <hip/hip_runtime.h>

// RobustSum: M = A@V; 3x { dist=cdist(M,V); w=1/(dist+eps); ww=w*A;
//                          M = (ww/rowsum(ww)) @ V }   (T=1.0)
// bf16 MFMA; tolerance = 2% of ref absmax.
//
// Round 10: revert r9's 256^2 experiment (regressed: MODE-1 is epilogue-
// memory-bound, not MFMA-bound). NEW: fuse the per-iteration pair
// (P=M@V^T + weight epilogue) and (M=W@V) into ONE kernel; W lives only in
// LDS (64x128 tile), never in HBM (-134 MB/iter). Per block: 64-row stripe
// x 1024-j half; M resident in LDS (64 KB, staged once); j-tiles of 128:
//   ph1: P(64x128) over K=512, B1 dbuf (2x16 KB, glds, wait-at-top);
//   epilogue: w=rcp(sqrt(m2+v2-2P)+eps), x=w*A, l1 in regs, W->LDS (swz);
//   ph2: Macc(64x512 f32, regs) += W @ Vt-chunk (4x 128dx128j, T14
//        reg-staged 32 KB single buffer).
// Output: split-K=2 bf16 partials + 2-slot l1p -> existing reduce.
// LDS: Mlds 64K | B1 2x16K (Wt aliases buf0) | Bt 32K (slab aliases) = 128K.

typedef __bf16 bf16;
typedef bf16 bf16x4 __attribute__((ext_vector_type(4)));
typedef bf16 bf16x8 __attribute__((ext_vector_type(8)));
typedef float f32x4 __attribute__((ext_vector_type(4)));

#define S_DIM 2048
#define D_DIM 512
#define NB    4
#define EPSILON 0.01f

#define AS1 __attribute__((address_space(1)))
#define AS3 __attribute__((address_space(3)))

// ---------------- cast fp32 -> bf16 (vectorized x4) ----------------
__global__ void cast_kernel(const float* __restrict__ in, bf16* __restrict__ out, int n4) {
  int i = blockIdx.x * blockDim.x + threadIdx.x;
  if (i >= n4) return;
  float4 v = ((const float4*)in)[i];
  bf16x4 o = { (bf16)v.x, (bf16)v.y, (bf16)v.z, (bf16)v.w };
  ((bf16x4*)out)[i] = o;
}

// -- V preproc: V fp32 -> Vbf + Vt (bf16) + v2 row L2^2 (non-atomic) --
__global__ void vprep_kernel(const float* __restrict__ V, bf16* __restrict__ Vbf,
                             bf16* __restrict__ Vt, float* __restrict__ v2) {
  __shared__ float tile[64][68];
  int b  = blockIdx.y;
  int r0 = blockIdx.x * 64;
  const float* Vb = V   + (size_t)b * S_DIM * D_DIM;
  bf16*       Vfb = Vbf + (size_t)b * S_DIM * D_DIM;
  bf16*       Vtb = Vt  + (size_t)b * S_DIM * D_DIM;
  float*      v2b = v2  + (size_t)b * S_DIM;
  int tx = threadIdx.x & 15, ty = threadIdx.x >> 4;   // ty 0..15
  float acc2[4] = { 0.f, 0.f, 0.f, 0.f };
  for (int c = 0; c < 8; ++c) {
    int c0 = c * 64;
#pragma unroll
    for (int i = 0; i < 4; ++i) {
      int r = ty + i * 16;
      float4 v = *(const float4*)(Vb + (size_t)(r0 + r) * D_DIM + (c0 + tx * 4));
      tile[r][tx * 4 + 0] = v.x; tile[r][tx * 4 + 1] = v.y;
      tile[r][tx * 4 + 2] = v.z; tile[r][tx * 4 + 3] = v.w;
      bf16x4 o = { (bf16)v.x, (bf16)v.y, (bf16)v.z, (bf16)v.w };
      *(bf16x4*)(Vfb + (size_t)(r0 + r) * D_DIM + (c0 + tx * 4)) = o;
#pragma unroll
      for (int j = 0; j < 4; ++j) { float f = (float)o[j]; acc2[i] += f * f; }
    }
    __syncthreads();
#pragma unroll
    for (int i = 0; i < 4; ++i) {
      int cc = ty + i * 16;
      bf16x4 o = { (bf16)tile[tx * 4 + 0][cc], (bf16)tile[tx * 4 + 1][cc],
                   (bf16)tile[tx * 4 + 2][cc], (bf16)tile[tx * 4 + 3][cc] };
      *(bf16x4*)(Vtb + (size_t)(c0 + cc) * S_DIM + (r0 + tx * 4)) = o;
    }
    __syncthreads();   // tile reused next chunk
  }
#pragma unroll
  for (int i = 0; i < 4; ++i) {
    float s = acc2[i];
    s += __shfl_xor(s, 1); s += __shfl_xor(s, 2);
    s += __shfl_xor(s, 4); s += __shfl_xor(s, 8);
    if (tx == 0) v2b[r0 + ty + i * 16] = s;
  }
}

// ---------------- fused iteration kernel ----------------
// grid (js 2, ir 32, b 4) = 256 blocks, 512 threads (8 waves).
__global__ __launch_bounds__(512, 2)
void fused_kernel(const bf16* __restrict__ Mbf, const bf16* __restrict__ Vbf,
                  const bf16* __restrict__ Vt, const bf16* __restrict__ Abf,
                  const float* __restrict__ m2, const float* __restrict__ v2,
                  bf16* __restrict__ part, float* __restrict__ l1p) {
  const int b  = blockIdx.z;
  const int i0 = blockIdx.y * 64;
  const int js = blockIdx.x;           // 0..1 -> j half
  const int jbase = js * 1024;

  const bf16* Mb = Mbf + (size_t)b * S_DIM * D_DIM;
  const bf16* Vb = Vbf + (size_t)b * S_DIM * D_DIM;
  const bf16* Tb = Vt  + (size_t)b * S_DIM * D_DIM;   // [d][s]
  const bf16* Ab = Abf + (size_t)b * S_DIM * S_DIM;
  const float* m2b = m2 + (size_t)b * S_DIM;
  const float* v2b = v2 + (size_t)b * S_DIM;

  __shared__ bf16 smem[65536];             // 128 KiB exactly
  bf16* Mlds = smem;                       // [kt 8][64 rows][64 k]  64 KB
  bf16* B1   = smem + 32768;               // 2 x [128 j][64 k] 16 KB each
  bf16* Wt   = smem + 32768;               // [64 i][128 j] 16 KB (aliases B1 buf0)
  bf16* Bt   = smem + 49152;               // [128 d][128 j] 32 KB
  float* l1lds = (float*)(smem + 32768);   // 2x64 f32 (final, aliases B1)
  float* slab  = (float*)(smem + 49152);   // 16x512 f32 (final, aliases Bt)

  const int tid  = threadIdx.x;
  const int w    = tid >> 6;      // wave 0..7
  const int lane = tid & 63;
  const int pr   = w >> 1;        // 0..3 -> 16-row group
  const int pc   = w & 1;         // 0..1 -> 64-j / 64-d half
  const int q    = lane >> 4;
  const int c16  = lane & 15;
  const int x7   = c16 & 7;
  const int srow  = lane >> 3;           // 0..7 (8-row staging)
  const int schk  = (lane & 7) ^ srow;   // pre-swizzled source chunk
  const int srow4 = lane >> 4;           // 0..3 (4-row staging, 16 chunks)
  const int lchk  = lane & 15;

  f32x4 acc2[16] = {};                   // Macc: rows pr*16(+q*4+r), cols ch*128+pc*64+n*16+c16
  float l1acc[4] = { 0.f, 0.f, 0.f, 0.f };
  uint4 btr[4];

  // ---- stage M resident (64x512, 8 k-tiles) ----
#pragma unroll
  for (int kt = 0; kt < 8; ++kt)
    __builtin_amdgcn_global_load_lds(
        (const AS1 void*)(Mb + (size_t)(i0 + w * 8 + srow) * D_DIM + kt * 64 + schk * 8),
        (AS3 void*)(Mlds + kt * 4096 + w * 512), 16, 0, 0);

  float m2v[4];
#pragma unroll
  for (int r = 0; r < 4; ++r) m2v[r] = m2b[i0 + pr * 16 + q * 4 + r];

  for (int jt = 0; jt < 8; ++jt) {
    const int j0 = jbase + jt * 128;
    // guard: Wt/B1/Bt rewrites vs previous j-tile's readers
    __builtin_amdgcn_s_barrier();

    // stage B1 kt=0 into buf0 + issue Bt ch0 into regs
#pragma unroll
    for (int it = 0; it < 2; ++it)
      __builtin_amdgcn_global_load_lds(
          (const AS1 void*)(Vb + (size_t)(j0 + it * 64 + w * 8 + srow) * D_DIM + schk * 8),
          (AS3 void*)(B1 + (it * 64 + w * 8) * 64), 16, 0, 0);
#pragma unroll
    for (int it = 0; it < 4; ++it) {
      int row = it * 32 + w * 4 + srow4;
      btr[it] = *(const uint4*)(Tb + (size_t)row * S_DIM + j0 + lchk * 8);
    }

    // ---- phase 1: P(64x128) over K=512, B1 double-buffered ----
    f32x4 acc1[4] = {};
    for (int kt = 0; kt < 8; ++kt) {
      const int rb = kt & 1;
      asm volatile("s_waitcnt vmcnt(0)" ::: "memory");  // stage(kt) complete
      __builtin_amdgcn_s_barrier();                     // buf rb^1 free to restage
      if (kt < 7) {
#pragma unroll
        for (int it = 0; it < 2; ++it)
          __builtin_amdgcn_global_load_lds(
              (const AS1 void*)(Vb + (size_t)(j0 + it * 64 + w * 8 + srow) * D_DIM + (kt + 1) * 64 + schk * 8),
              (AS3 void*)(B1 + (rb ^ 1) * 8192 + (it * 64 + w * 8) * 64), 16, 0, 0);
      }
      const bf16* lb = B1 + rb * 8192;
      __builtin_amdgcn_s_setprio(1);
#pragma unroll
      for (int kk = 0; kk < 2; ++kk) {
        const int p = ((kk << 2) + q) ^ x7;
        bf16x8 af = *(const bf16x8*)(Mlds + kt * 4096 + (pr * 16 + c16) * 64 + p * 8);
#pragma unroll
        for (int n2 = 0; n2 < 4; ++n2) {
          bf16x8 bv = *(const bf16x8*)(lb + (pc * 64 + n2 * 16 + c16) * 64 + p * 8);
          acc1[n2] = __builtin_amdgcn_mfma_f32_16x16x32_bf16(af, bv, acc1[n2], 0, 0, 0);
        }
      }
      __builtin_amdgcn_s_setprio(0);
    }

    // ---- epilogue: w = rcp(sqrt(max(m2+v2-2P,0))+eps); x = w*A; W->LDS ----
    float v2v[4];
#pragma unroll
    for (int n2 = 0; n2 < 4; ++n2) v2v[n2] = v2b[j0 + pc * 64 + n2 * 16 + c16];
#pragma unroll
    for (int n2 = 0; n2 < 4; ++n2)
#pragma unroll
      for (int r = 0; r < 4; ++r) {
        const int rr = pr * 16 + q * 4 + r;
        const int jl = pc * 64 + n2 * 16 + c16;
        float d2 = fmaxf(m2v[r] + v2v[n2] - 2.f * acc1[n2][r], 0.f);
        float w_ = __builtin_amdgcn_rcpf(__builtin_amdgcn_sqrtf(d2) + EPSILON);
        float a  = (float)Ab[(size_t)(i0 + rr) * S_DIM + j0 + jl];
        float x  = w_ * a;
        l1acc[r] += fabsf(x);
        Wt[rr * 128 + (((jl >> 3) ^ (rr & 7)) << 3) + (jl & 7)] = (bf16)x;
      }
    // Bt ch0 regs landed (drained by kt-loop waits); write + issue ch1
#pragma unroll
    for (int it = 0; it < 4; ++it) {
      int row = it * 32 + w * 4 + srow4;
      *(uint4*)(Bt + row * 128 + ((lchk ^ (row & 7)) << 3)) = btr[it];
    }
#pragma unroll
    for (int it = 0; it < 4; ++it) {
      int row = it * 32 + w * 4 + srow4;
      btr[it] = *(const uint4*)(Tb + (size_t)(128 + row) * S_DIM + j0 + lchk * 8);
    }
    asm volatile("s_waitcnt lgkmcnt(0)" ::: "memory");
    __builtin_amdgcn_s_barrier();

    // ---- phase 2: Macc += W(64x128) @ Vt-chunks (4 x 128d) ----
#pragma unroll
    for (int ch = 0; ch < 4; ++ch) {
      __builtin_amdgcn_s_setprio(1);
#pragma unroll
      for (int kk = 0; kk < 4; ++kk) {
        const int p = ((kk << 2) + q) ^ x7;
        bf16x8 aw = *(const bf16x8*)(Wt + (pr * 16 + c16) * 128 + p * 8);
#pragma unroll
        for (int n = 0; n < 4; ++n) {
          bf16x8 bv = *(const bf16x8*)(Bt + (pc * 64 + n * 16 + c16) * 128 + p * 8);
          acc2[ch * 4 + n] = __builtin_amdgcn_mfma_f32_16x16x32_bf16(aw, bv, acc2[ch * 4 + n], 0, 0, 0);
        }
      }
      __builtin_amdgcn_s_setprio(0);
      if (ch < 3) {
        __builtin_amdgcn_s_barrier();                     // all done reading Bt[ch]
        asm volatile("s_waitcnt vmcnt(0)" ::: "memory");  // ch+1 regs landed
#pragma unroll
        for (int it = 0; it < 4; ++it) {
          int row = it * 32 + w * 4 + srow4;
          *(uint4*)(Bt + row * 128 + ((lchk ^ (row & 7)) << 3)) = btr[it];
        }
        if (ch < 2) {
#pragma unroll
          for (int it = 0; it < 4; ++it) {
            int row = it * 32 + w * 4 + srow4;
            btr[it] = *(const uint4*)(Tb + (size_t)((ch + 2) * 128 + row) * S_DIM + j0 + lchk * 8);
          }
        }
        asm volatile("s_waitcnt lgkmcnt(0)" ::: "memory");
        __builtin_amdgcn_s_barrier();
      }
    }
  }

  // ---- final: l1 merge -> l1p ; Macc -> bf16 partial via slab ----
  __builtin_amdgcn_s_barrier();     // last j-tile's Wt/Bt reads done
#pragma unroll
  for (int r = 0; r < 4; ++r) {
    float s = l1acc[r];
    s += __shfl_xor(s, 1); s += __shfl_xor(s, 2);
    s += __shfl_xor(s, 4); s += __shfl_xor(s, 8);
    if (c16 == 0) l1lds[pc * 64 + pr * 16 + q * 4 + r] = s;
  }
  asm volatile("s_waitcnt lgkmcnt(0)" ::: "memory");
  __builtin_amdgcn_s_barrier();
  if (tid < 64)
    l1p[((size_t)js * NB + b) * S_DIM + i0 + tid] = l1lds[tid] + l1lds[64 + tid];

  bf16* pp = part + ((size_t)js * NB + b) * (size_t)S_DIM * D_DIM;
#pragma unroll
  for (int g = 0; g < 4; ++g) {
    __builtin_amdgcn_s_barrier();   // slab region free
    if (pr == g) {
#pragma unroll
      for (int ch = 0; ch < 4; ++ch)
#pragma unroll
        for (int n = 0; n < 4; ++n)
#pragma unroll
          for (int r = 0; r < 4; ++r)
            slab[(q * 4 + r) * 512 + ch * 128 + pc * 64 + n * 16 + c16] = acc2[ch * 4 + n][r];
    }
    asm volatile("s_waitcnt lgkmcnt(0)" ::: "memory");
    __builtin_amdgcn_s_barrier();
    {
      const int row = tid >> 5, col = (tid & 31) * 16;
      const float* sp = slab + row * 512 + col;
      float4 f0 = *(const float4*)(sp + 0);
      float4 f1 = *(const float4*)(sp + 4);
      float4 f2 = *(const float4*)(sp + 8);
      float4 f3 = *(const float4*)(sp + 12);
      bf16x8 o0 = { (bf16)f0.x, (bf16)f0.y, (bf16)f0.z, (bf16)f0.w,
                    (bf16)f1.x, (bf16)f1.y, (bf16)f1.z, (bf16)f1.w };
      bf16x8 o1 = { (bf16)f2.x, (bf16)f2.y, (bf16)f2.z, (bf16)f2.w,
                    (bf16)f3.x, (bf16)f3.y, (bf16)f3.z, (bf16)f3.w };
      bf16* op = pp + (size_t)(i0 + g * 16 + row) * D_DIM + col;
      *(bf16x8*)(op)     = o0;
      *(bf16x8*)(op + 8) = o1;
    }
  }
}

// ---------------- NT GEMM 128^2 (MODE 4): split-K=2 bf16 partials ----------------
template <int MODE>
__global__ __launch_bounds__(256, 4)
void gemm_kernel(const bf16* __restrict__ Amat, const bf16* __restrict__ Bmat,
                 int M, int N, int K,
                 bf16* __restrict__ Cp,
                 const float* __restrict__ m2, const float* __restrict__ v2,
                 const bf16* __restrict__ Aw, bf16* __restrict__ Wout,
                 float* __restrict__ l1p) {
  int bz, ks, kbeg, kend;
  if (MODE == 4) { bz = blockIdx.z >> 1; ks = blockIdx.z & 1; kbeg = ks * (K >> 1); kend = kbeg + (K >> 1); }
  else           { bz = blockIdx.z;      ks = 0;              kbeg = 0;             kend = K; }
  const int row0 = blockIdx.y * 128;
  const int col0 = blockIdx.x * 128;
  const bf16* Ab = Amat + (size_t)bz * M * K;
  const bf16* Bb = Bmat + (size_t)bz * N * K;

  __shared__ char smem[33792];
  bf16*  ldsA = (bf16*)smem;
  bf16*  ldsB = (bf16*)(smem + 16384);
  float* ldsW = (float*)smem;

  const int tid  = threadIdx.x;
  const int wave = tid >> 6;
  const int lane = tid & 63;
  const int wr   = wave >> 1;
  const int wc   = wave & 1;
  const int q    = lane >> 4;
  const int c16  = lane & 15;

  const int srow = lane >> 3;
  const int scol = ((lane & 7) ^ srow) * 8;

  f32x4 acc[4][4] = {};

  for (int k0 = kbeg; k0 < kend; k0 += 64) {
#pragma unroll
    for (int i = 0; i < 4; ++i) {
      int slot = wave * 4 + i;
      int r = slot * 8 + srow;
      __builtin_amdgcn_global_load_lds(
          (const AS1 void*)(Ab + (size_t)(row0 + r) * K + (k0 + scol)),
          (AS3 void*)(ldsA + slot * 512), 16, 0, 0);
      __builtin_amdgcn_global_load_lds(
          (const AS1 void*)(Bb + (size_t)(col0 + r) * K + (k0 + scol)),
          (AS3 void*)(ldsB + slot * 512), 16, 0, 0);
    }
    __syncthreads();

#pragma unroll
    for (int kk = 0; kk < 2; ++kk) {
      bf16x8 afr[4], bfr[4];
#pragma unroll
      for (int mt = 0; mt < 4; ++mt) {
        int R = wr * 64 + mt * 16 + c16;
        int p = ((kk << 2) + q) ^ (c16 & 7);
        afr[mt] = *(const bf16x8*)(ldsA + (size_t)R * 64 + p * 8);
      }
#pragma unroll
      for (int nt = 0; nt < 4; ++nt) {
        int R = wc * 64 + nt * 16 + c16;
        int p = ((kk << 2) + q) ^ (c16 & 7);
        bfr[nt] = *(const bf16x8*)(ldsB + (size_t)R * 64 + p * 8);
      }
#pragma unroll
      for (int mt = 0; mt < 4; ++mt)
#pragma unroll
        for (int nt = 0; nt < 4; ++nt)
          acc[mt][nt] = __builtin_amdgcn_mfma_f32_16x16x32_bf16(afr[mt], bfr[nt], acc[mt][nt], 0, 0, 0);
    }
    __syncthreads();
  }

  const int lr  = tid >> 3;
  const int sub = tid & 7;
#pragma unroll
  for (int h = 0; h < 2; ++h) {
    __syncthreads();
    if (wr == h) {
#pragma unroll
      for (int mt = 0; mt < 4; ++mt)
#pragma unroll
        for (int nt = 0; nt < 4; ++nt)
#pragma unroll
          for (int r = 0; r < 4; ++r)
            ldsW[(mt * 16 + q * 4 + r) * 132 + wc * 64 + nt * 16 + c16] = acc[mt][nt][r];
    }
    __syncthreads();
#pragma unroll
    for (int h2 = 0; h2 < 2; ++h2) {
      int rloc = lr + 32 * h2;
      int gi = row0 + 64 * h + rloc;
      const float* wp = ldsW + rloc * 132 + sub * 16;
      float4 w0 = *(const float4*)(wp + 0);
      float4 w1 = *(const float4*)(wp + 4);
      float4 w2 = *(const float4*)(wp + 8);
      float4 w3 = *(const float4*)(wp + 12);
      float wv_[16] = { w0.x, w0.y, w0.z, w0.w, w1.x, w1.y, w1.z, w1.w,
                        w2.x, w2.y, w2.z, w2.w, w3.x, w3.y, w3.z, w3.w };
      bf16* Cb = Cp + ((size_t)ks * NB + bz) * ((size_t)M * N);
      bf16x8 o0, o1;
#pragma unroll
      for (int e = 0; e < 8; ++e) { o0[e] = (bf16)wv_[e]; o1[e] = (bf16)wv_[e + 8]; }
      bf16* op = Cb + (size_t)gi * N + (col0 + sub * 16);
      *(bf16x8*)(op)     = o0;
      *(bf16x8*)(op + 8) = o1;
    }
  }
}

// ---------------- reduce split-K=2 bf16 partials ----------------
// RMODE 0: Mbf + m2 ;  1: scale 1/l1 -> Mbf + m2 ;  2: scale 1/l1 -> fp32 out
template <int RMODE>
__global__ void reduce_kernel(const bf16* __restrict__ part, const float* __restrict__ l1p,
                              bf16* __restrict__ Mo, float* __restrict__ Fo,
                              float* __restrict__ m2) {
  int wave = threadIdx.x >> 6, lane = threadIdx.x & 63;
  int rg = blockIdx.x * 4 + wave;          // 0..NB*S-1
  const bf16* p0 = part + (size_t)rg * D_DIM + lane * 8;
  const bf16* p1 = p0 + (size_t)NB * S_DIM * D_DIM;
  bf16x8 a = *(const bf16x8*)p0;
  bf16x8 b = *(const bf16x8*)p1;
  float v[8];
#pragma unroll
  for (int e = 0; e < 8; ++e) v[e] = (float)a[e] + (float)b[e];
  float sc = 1.f;
  if (RMODE >= 1) {
    int bb = rg >> 11, row = rg & (S_DIM - 1);
    float l1v = 0.f;
#pragma unroll
    for (int e = 0; e < 2; ++e) l1v += l1p[((size_t)e * NB + bb) * S_DIM + row];
    sc = __builtin_amdgcn_rcpf(fmaxf(l1v, 1e-12f));
  }
  float s = 0.f;
#pragma unroll
  for (int e = 0; e < 8; ++e) { v[e] *= sc; s += v[e] * v[e]; }
  if (RMODE == 2) {
    float4 o0 = { v[0], v[1], v[2], v[3] }, o1 = { v[4], v[5], v[6], v[7] };
    float* op = Fo + (size_t)rg * D_DIM + lane * 8;
    *(float4*)(op) = o0; *(float4*)(op + 4) = o1;
  } else {
    bf16x8 o;
#pragma unroll
    for (int e = 0; e < 8; ++e) o[e] = (bf16)v[e];
    *(bf16x8*)(Mo + (size_t)rg * D_DIM + lane * 8) = o;
#pragma unroll
    for (int off = 32; off > 0; off >>= 1) s += __shfl_xor(s, off);
    if (lane == 0) m2[rg] = s;
  }
}

extern "C" void kernel_launch(void* const* d_in, const int* in_sizes, int n_in,
                              void* d_out, int out_size, void* d_ws, size_t ws_size,
                              hipStream_t stream) {
  const float* A = (const float*)d_in[0];  // (4, 2048, 2048)
  const float* V = (const float*)d_in[1];  // (4, 2048, 512)
  float* out = (float*)d_out;              // (4, 2048, 512) fp32

  char* ws = (char*)d_ws;
  bf16* Abf = (bf16*)ws;   ws += (size_t)NB * S_DIM * S_DIM * 2;       // 33.5 MB
  bf16* Vbf = (bf16*)ws;   ws += (size_t)NB * S_DIM * D_DIM * 2;       //  8.4 MB
  bf16* Vt  = (bf16*)ws;   ws += (size_t)NB * S_DIM * D_DIM * 2;       //  8.4 MB
  bf16* Mbf = (bf16*)ws;   ws += (size_t)NB * S_DIM * D_DIM * 2;       //  8.4 MB
  bf16* part = (bf16*)ws;  ws += (size_t)2 * NB * S_DIM * D_DIM * 2;   // 16.8 MB
  float* v2 = (float*)ws;  ws += (size_t)NB * S_DIM * 4;
  float* m2 = (float*)ws;  ws += (size_t)NB * S_DIM * 4;
  float* l1p = (float*)ws; ws += (size_t)2 * NB * S_DIM * 4;           // 64 KB

  int nA4 = NB * S_DIM * S_DIM / 4;
  cast_kernel<<<nA4 / 256, 256, 0, stream>>>(A, Abf, nA4);
  vprep_kernel<<<dim3(S_DIM / 64, NB), 256, 0, stream>>>(V, Vbf, Vt, v2);

  // M0 = A @ V  (split-K=2 bf16 partials -> reduce with m2)
  gemm_kernel<4><<<dim3(D_DIM / 128, S_DIM / 128, NB * 2), 256, 0, stream>>>(
      Abf, Vt, S_DIM, D_DIM, S_DIM, part, nullptr, nullptr, nullptr, nullptr, nullptr);
  reduce_kernel<0><<<NB * S_DIM / 4, 256, 0, stream>>>(part, nullptr, Mbf, nullptr, m2);

  for (int it = 0; it < 3; ++it) {
    // fused: P=M@V^T -> w -> W(LDS only) -> M_part = W@V ; l1 partials
    fused_kernel<<<dim3(2, S_DIM / 64, NB), 512, 0, stream>>>(
        Mbf, Vbf, Vt, Abf, m2, v2, part, l1p);
    if (it < 2)
      reduce_kernel<1><<<NB * S_DIM / 4, 256, 0, stream>>>(part, l1p, Mbf, nullptr, m2);
    else
      reduce_kernel<2><<<NB * S_DIM / 4, 256, 0, stream>>>(part, l1p, nullptr, out, nullptr);
  }
}